// Round 8
// baseline (240.289 us; speedup 1.0000x reference)
//
#include <hip/hip_runtime.h>
#include <hip/hip_fp16.h>
#include <math.h>

// Pipeline (4 launches) — R7 structure + chunked two-pass softmax in attn (R8):
//  memset:   zero tcnt + bucket_count
//  classify: split node ids by type into list0/list1 (wave-aggregated atomics)
//  proj_scatter (FUSED): one grid, branch on blockIdx.
//     - blocks [0, nsort): bucket_scatter at 256 thr/block, 4 edges/thread via
//       int4 loads (chunk=4096). Edges into per-bucket slabs bdata[b*CAP..]
//       (bucket = dst>>5, 32 dsts -> one attn block each). R2 lesson: scatter
//       is latency-bound -> maximize blocks+ILP.
//     - blocks [nsort, nsort+PGRID): per-type register-tiled GEMM
//       z[list[i]] = A[list[i]] @ W, output stored FP16 (R7: halves gather
//       bytes, FETCH 164->71 MB, absmax 0.078 < 0.174).
//  attn_fused: one 512-thr block per 32-dst bucket. Two cheap LDS passes build
//     per-dst CSR (ushort srcs), then 8 waves x 4 dsts, 16 lanes/edge.
//     R8: chunked TWO-PASS softmax per dst (chunks of 32 edges): pass A =
//     dot+chunk-max only (no exp/rescale on the serial chain; 8 independent
//     loads pipeline); ONE rescale per chunk; pass B = 8 independent exps +
//     FMA accumulate with ZERO loads/shuffles (z fragments kept in regs).
//     R7 diagnosis: attn was VALU-chain-bound (VALUBusy 56%, HBM 20%) on the
//     per-iteration online-softmax update; mean degree 25 -> 1 chunk/dst.
//     R6 lesson: grid.sync costs ~130us on MI355X -> stay multi-dispatch.
// Assumes N <= 65536 (src packed into low 16 bits of bdata; NBUK <= 2048).

#define F 64
#define TM 128
#define TK 64
#define BSH 5                    // bucket = dst >> 5 (32 dsts per bucket)
#define CHUNK 4096               // edges per scatter block (mult of 4)
#define CAP 1280                 // slab capacity per bucket (mean 800, +17 sigma)
#define HCAP 1280                // per-bucket LDS list capacity

#define PROJ_LDS (128 * (TK + 1) * 4 + TK * F * 4)   // 33280 + 16384 = 49664 B

__global__ void classify_kernel(const int* __restrict__ node_type, int* __restrict__ tcnt,
                                int* __restrict__ list0, int* __restrict__ list1, int n) {
    int i = blockIdx.x * 256 + threadIdx.x;
    if (i < n) {
        int lane = threadIdx.x & 63;
        int t = node_type[i];
        unsigned long long b1 = __ballot(t == 1);
        unsigned long long ba = __ballot(1);
        unsigned long long mlt = (1ull << lane) - 1ull;
        int r1 = __popcll(b1 & mlt);
        int r0 = __popcll(ba & ~b1 & mlt);
        int base0, base1;
        if (lane == 0) {
            base1 = atomicAdd(&tcnt[1], __popcll(b1));
            base0 = atomicAdd(&tcnt[0], __popcll(ba & ~b1));
        }
        base0 = __shfl(base0, 0, 64);
        base1 = __shfl(base1, 0, 64);
        if (t == 1) list1[base1 + r1] = i;
        else        list0[base0 + r0] = i;
    }
}

__global__ __launch_bounds__(256, 2)
void proj_scatter(const float* __restrict__ d_sim, const float* __restrict__ m_sim,
                  const float* __restrict__ W_d, const float* __restrict__ W_m,
                  const int* __restrict__ tcnt, const int* __restrict__ list0,
                  const int* __restrict__ list1, unsigned short* __restrict__ zh,
                  const int* __restrict__ dst, const int* __restrict__ src,
                  int* __restrict__ bucket_count, int* __restrict__ bucket_data,
                  int e, int nbuk, int nsort) {
    __shared__ __align__(16) char smem[PROJ_LDS];    // union: proj 49664B / scatter 24576B
    int bid = blockIdx.x;

    if (bid < nsort) {
        // ---- bucket_scatter branch: 256 thr, 4 edges/thread via int4 ----
        int* hist  = (int*)smem;        // [2048]
        int* bbase = hist + 2048;       // [2048]
        int* rk    = bbase + 2048;      // [2048]
        for (int i = threadIdx.x; i < nbuk; i += 256) { hist[i] = 0; rk[i] = 0; }
        __syncthreads();
        int beg = bid * CHUNK, end = min(e, beg + CHUNK);
        for (int i = beg + (int)threadIdx.x * 4; i < end; i += 1024) {
            int4 d4 = *(const int4*)(dst + i);      // e mult of 4 assumed
            atomicAdd(&hist[d4.x >> BSH], 1);
            atomicAdd(&hist[d4.y >> BSH], 1);
            atomicAdd(&hist[d4.z >> BSH], 1);
            atomicAdd(&hist[d4.w >> BSH], 1);
        }
        __syncthreads();
        for (int i = threadIdx.x; i < nbuk; i += 256)
            bbase[i] = hist[i] ? atomicAdd(&bucket_count[i], hist[i]) : 0;
        __syncthreads();
        for (int i = beg + (int)threadIdx.x * 4; i < end; i += 1024) {
            int4 d4 = *(const int4*)(dst + i);
            int4 s4 = *(const int4*)(src + i);
            int b0 = d4.x >> BSH, b1 = d4.y >> BSH, b2 = d4.z >> BSH, b3 = d4.w >> BSH;
            int r0 = atomicAdd(&rk[b0], 1);
            int r1 = atomicAdd(&rk[b1], 1);
            int r2 = atomicAdd(&rk[b2], 1);
            int r3 = atomicAdd(&rk[b3], 1);
            int p0 = bbase[b0] + r0, p1 = bbase[b1] + r1;
            int p2 = bbase[b2] + r2, p3 = bbase[b3] + r3;
            if (p0 < CAP) bucket_data[(size_t)b0 * CAP + p0] = ((d4.x & 31) << 16) | s4.x;
            if (p1 < CAP) bucket_data[(size_t)b1 * CAP + p1] = ((d4.y & 31) << 16) | s4.y;
            if (p2 < CAP) bucket_data[(size_t)b2 * CAP + p2] = ((d4.z & 31) << 16) | s4.z;
            if (p3 < CAP) bucket_data[(size_t)b3 * CAP + p3] = ((d4.w & 31) << 16) | s4.w;
        }
        return;
    }

    // ------------------------- proj_gemm branch --------------------------
    int pb = bid - nsort;
    int ty = pb & 1;
    int cnt = tcnt[ty];
    int base = (pb >> 1) * TM;
    if (base >= cnt) return;
    const int*   list = ty ? list1 : list0;
    const float* A    = ty ? d_sim : m_sim;
    const float* W    = ty ? W_d   : W_m;

    float (*sA)[TK + 1] = (float (*)[TK + 1])smem;
    float (*sW)[F]      = (float (*)[F])(smem + 128 * (TK + 1) * 4);

    int rg = threadIdx.x >> 4;
    int cg = threadIdx.x & 15;

    int srow_node[8];
    #pragma unroll
    for (int j = 0; j < 8; j++) {
        int idx = (int)threadIdx.x + 256 * j;
        int li = base + (idx >> 4);
        if (li >= cnt) li = cnt - 1;
        srow_node[j] = list[li];
    }

    float acc[8][4] = {};
    for (int kc = 0; kc < 256; kc += TK) {
        __syncthreads();
        #pragma unroll
        for (int j = 0; j < 8; j++) {
            int idx = (int)threadIdx.x + 256 * j;
            int r = idx >> 4, f4 = idx & 15;
            float4 v = *(const float4*)(A + (size_t)srow_node[j] * 256 + kc + f4 * 4);
            sA[r][f4 * 4 + 0] = v.x;
            sA[r][f4 * 4 + 1] = v.y;
            sA[r][f4 * 4 + 2] = v.z;
            sA[r][f4 * 4 + 3] = v.w;
        }
        #pragma unroll
        for (int j = 0; j < 4; j++) {
            int idx = (int)threadIdx.x + 256 * j;
            int k = idx >> 4, f4 = idx & 15;
            float4 v = *(const float4*)(W + (size_t)(kc + k) * F + f4 * 4);
            *(float4*)&sW[k][f4 * 4] = v;
        }
        __syncthreads();
        #pragma unroll 4
        for (int k = 0; k < TK; k++) {
            float4 wv = *(const float4*)&sW[k][cg * 4];
            float a[8];
            #pragma unroll
            for (int i = 0; i < 8; i++) a[i] = sA[rg * 8 + i][k];
            #pragma unroll
            for (int i = 0; i < 8; i++) {
                acc[i][0] = fmaf(a[i], wv.x, acc[i][0]);
                acc[i][1] = fmaf(a[i], wv.y, acc[i][1]);
                acc[i][2] = fmaf(a[i], wv.z, acc[i][2]);
                acc[i][3] = fmaf(a[i], wv.w, acc[i][3]);
            }
        }
    }
    #pragma unroll
    for (int i = 0; i < 8; i++) {
        int li = base + rg * 8 + i;
        if (li < cnt) {
            int node = list[li];
            __half2 ha = __floats2half2_rn(acc[i][0], acc[i][1]);
            __half2 hb = __floats2half2_rn(acc[i][2], acc[i][3]);
            uint2 u;
            u.x = *(unsigned int*)&ha;
            u.y = *(unsigned int*)&hb;
            *(uint2*)(zh + (size_t)node * F + cg * 4) = u;   // 8B store, 16 lanes = 128B row
        }
    }
}

__global__ __launch_bounds__(512)
void attn_fused(const unsigned short* __restrict__ zh, const int* __restrict__ bucket_count,
                const int* __restrict__ bucket_data, float* __restrict__ out, int n) {
    __shared__ unsigned short ssrc[HCAP];
    __shared__ int cnt[32], excl[32], cur[32];
    int b = blockIdx.x;
    int dbase = b << BSH;
    const int* __restrict__ bd = bucket_data + (size_t)b * CAP;
    int len = min(bucket_count[b], CAP);
    int tid = threadIdx.x;

    if (tid < 32) { cnt[tid] = 0; cur[tid] = 0; }
    __syncthreads();
    // pass 1: per-dst counts (bucket holds only our 32 dsts)
    for (int i = tid; i < len; i += 512)
        atomicAdd(&cnt[bd[i] >> 16], 1);
    __syncthreads();
    if (tid < 32) {                   // 32-wide shfl exclusive scan (one wave)
        int v = cnt[tid];
        int s = v;
        #pragma unroll
        for (int off = 1; off < 32; off <<= 1) {
            int t = __shfl_up(s, off, 32);
            if (tid >= off) s += t;
        }
        excl[tid] = s - v;
    }
    __syncthreads();
    // pass 2: scatter srcs into LDS grouped by dst
    for (int i = tid; i < len; i += 512) {
        int v = bd[i];
        int d5 = v >> 16;
        int r = atomicAdd(&cur[d5], 1);
        int pos = excl[d5] + r;
        if (pos < HCAP) ssrc[pos] = (unsigned short)(v & 0xFFFF);
    }
    __syncthreads();

    // attention: wave wv handles dsts d5 = wv + 8k; 16 lanes/edge.
    // Chunked two-pass softmax (R8): pass A dot+max (no exp on chain),
    // one rescale per 32-edge chunk, pass B exp+acc with zero loads.
    int lane = tid & 63;
    int wv = tid >> 6;
    int g = lane >> 4, r = lane & 15;
    for (int k = 0; k < 4; k++) {
        int d5 = wv + 8 * k;
        int node = dbase + d5;
        if (node >= n) continue;
        int lbeg = excl[d5];
        int lcnt = min(cnt[d5], max(0, HCAP - lbeg));
        uint2 ud = *(const uint2*)(zh + (size_t)node * F + r * 4);
        float2 d0 = __half22float2(*(const __half2*)&ud.x);
        float2 d1 = __half22float2(*(const __half2*)&ud.y);
        float m = -3.402823466e38f, l = 0.f;
        float4 acc = {0.f, 0.f, 0.f, 0.f};
        for (int j0 = 0; j0 < lcnt; j0 += 32) {
            float ev[8];
            uint2 uu[8];
            float cm = -3.402823466e38f;          // finite init: masked e=-inf never
            #pragma unroll                        // makes m=-inf (no NaN in exp)
            for (int it = 0; it < 8; it++) {
                int jj = j0 + it * 4 + g;
                int s = ssrc[lbeg + min(jj, lcnt - 1)];   // LDS broadcast per group
                uint2 u = *(const uint2*)(zh + (size_t)s * F + r * 4);
                uu[it] = u;
                float2 f0 = __half22float2(*(const __half2*)&u.x);
                float2 f1 = __half22float2(*(const __half2*)&u.y);
                float p = fmaf(f0.x, d0.x, fmaf(f0.y, d0.y, fmaf(f1.x, d1.x, f1.y * d1.y)));
                p += __shfl_xor(p, 1, 64);
                p += __shfl_xor(p, 2, 64);
                p += __shfl_xor(p, 4, 64);
                p += __shfl_xor(p, 8, 64);
                float e = (p > 0.f) ? p : 0.2f * p;       // leaky_relu
                if (jj >= lcnt) e = -INFINITY;
                ev[it] = e;
                cm = fmaxf(cm, e);
            }
            // single rescale per chunk (amortizes the old per-iter update)
            float t = __expf(-fabsf(m - cm));
            bool gt = (cm > m);
            float sc = gt ? t : 1.f;
            m = gt ? cm : m;
            l *= sc;
            acc.x *= sc; acc.y *= sc; acc.z *= sc; acc.w *= sc;
            #pragma unroll
            for (int it = 0; it < 8; it++) {
                float w = __expf(ev[it] - m);     // 8 independent exps; masked -> 0
                float2 f0 = __half22float2(*(const __half2*)&uu[it].x);
                float2 f1 = __half22float2(*(const __half2*)&uu[it].y);
                l += w;
                acc.x = fmaf(w, f0.x, acc.x);
                acc.y = fmaf(w, f0.y, acc.y);
                acc.z = fmaf(w, f1.x, acc.z);
                acc.w = fmaf(w, f1.y, acc.w);
            }
        }
        // merge the 4 groups
        #pragma unroll
        for (int off = 16; off <= 32; off <<= 1) {
            float om = __shfl_xor(m, off, 64);
            float ol = __shfl_xor(l, off, 64);
            float4 oa;
            oa.x = __shfl_xor(acc.x, off, 64);
            oa.y = __shfl_xor(acc.y, off, 64);
            oa.z = __shfl_xor(acc.z, off, 64);
            oa.w = __shfl_xor(acc.w, off, 64);
            float t = __expf(-fabsf(m - om));
            bool gt = (om > m);
            float sc = gt ? t : 1.f;
            float so = gt ? 1.f : t;
            m = gt ? om : m;
            l = fmaf(l, sc, ol * so);
            acc.x = fmaf(acc.x, sc, oa.x * so);
            acc.y = fmaf(acc.y, sc, oa.y * so);
            acc.z = fmaf(acc.z, sc, oa.z * so);
            acc.w = fmaf(acc.w, sc, oa.w * so);
        }
        float inv = 1.f / fmaxf(l, 1e-16f);
        float4 o;
        o.x = acc.x * inv; o.y = acc.y * inv; o.z = acc.z * inv; o.w = acc.w * inv;
        o.x = (o.x > 0.f) ? o.x : (__expf(o.x) - 1.f);
        o.y = (o.y > 0.f) ? o.y : (__expf(o.y) - 1.f);
        o.z = (o.z > 0.f) ? o.z : (__expf(o.z) - 1.f);
        o.w = (o.w > 0.f) ? o.w : (__expf(o.w) - 1.f);
        if (g == 0) ((float4*)(out + (size_t)node * F))[r] = o;
    }
}

extern "C" void kernel_launch(void* const* d_in, const int* in_sizes, int n_in,
                              void* d_out, int out_size, void* d_ws, size_t ws_size,
                              hipStream_t stream) {
    const float* d_sim     = (const float*)d_in[0];
    const float* m_sim     = (const float*)d_in[1];
    const float* W_d       = (const float*)d_in[2];
    const float* W_m       = (const float*)d_in[3];
    const int*   node_type = (const int*)d_in[4];
    const int*   src       = (const int*)d_in[5];
    const int*   dst       = (const int*)d_in[6];
    float* out = (float*)d_out;

    const int N = in_sizes[4];
    const int E = in_sizes[5];
    const int NBUK = (N + 31) >> BSH;           // 1563 for N=50000 (<=2048 assumed)

    char* ws = (char*)d_ws;
    int*            tcnt   = (int*)ws;                          // 2
    int*            bcount = tcnt + 2;                          // 2048
    int             head   = (2 + 2048 + 3) & ~3;               // align to 16B
    unsigned short* zh     = (unsigned short*)(ws + (size_t)head * 4);  // N*F fp16
    int*            list0  = (int*)(zh + (size_t)N * F);        // N (offset mult of 128B)
    int*            list1  = list0 + N;                         // N
    int*            bdata  = list1 + N;                         // NBUK*CAP

    hipMemsetAsync(tcnt, 0, (size_t)(2 + 2048) * sizeof(int), stream);

    dim3 blk(256);
    classify_kernel<<<dim3((N + 255) / 256), blk, 0, stream>>>(node_type, tcnt, list0, list1, N);

    int nsort = (E + CHUNK - 1) / CHUNK;        // 306 for E=1.25M
    int pgrid = 2 * ((N + TM - 1) / TM);        // 782
    proj_scatter<<<dim3(nsort + pgrid), blk, 0, stream>>>(d_sim, m_sim, W_d, W_m,
                                                          tcnt, list0, list1, zh,
                                                          dst, src, bcount, bdata,
                                                          E, NBUK, nsort);
    attn_fused<<<dim3(NBUK), dim3(512), 0, stream>>>(zh, bcount, bdata, out, N);
}

// Round 9
// 234.585 us; speedup vs baseline: 1.0243x; 1.0243x over previous
//
#include <hip/hip_runtime.h>
#include <hip/hip_fp16.h>
#include <math.h>

// Pipeline (4 launches) — R7-proven structure + 1-deep gather prefetch (R9):
//  memset:   zero tcnt + bucket_count
//  classify: split node ids by type into list0/list1 (wave-aggregated atomics)
//  proj_scatter (FUSED): one grid, branch on blockIdx.
//     - blocks [0, nsort): bucket_scatter at 256 thr/block, 4 edges/thread via
//       int4 loads (chunk=4096). Edges into per-bucket slabs bdata[b*CAP..]
//       (bucket = dst>>5, 32 dsts -> one attn block each). R2 lesson: scatter
//       is latency-bound -> maximize blocks+ILP.
//     - blocks [nsort, nsort+PGRID): per-type register-tiled GEMM
//       z[list[i]] = A[list[i]] @ W, output stored FP16 (R7: halves gather
//       bytes, FETCH 164->71 MB, absmax 0.078 < 0.174).
//  attn_fused: one 512-thr block per 32-dst bucket. Two cheap LDS passes build
//     per-dst CSR (ushort srcs), then 8 waves x 4 dsts, 16 lanes/edge with the
//     R1/R7-measured-best ONLINE softmax (R8's chunked two-pass regressed:
//     54.5->59.6, VGPR 44, occupancy 30% -- reverted). R9: 1-deep software
//     prefetch of next edge's ssrc+z row so the ~200cy L2 gather latency hides
//     under the dot+shfl+softmax compute (R7 diagnosis: 44% stall at 56% VALU).
//     R6 lesson: grid.sync costs ~130us on MI355X -> stay multi-dispatch.
// Assumes N <= 65536 (src packed into low 16 bits of bdata; NBUK <= 2048).

#define F 64
#define TM 128
#define TK 64
#define BSH 5                    // bucket = dst >> 5 (32 dsts per bucket)
#define CHUNK 4096               // edges per scatter block (mult of 4)
#define CAP 1280                 // slab capacity per bucket (mean 800, +17 sigma)
#define HCAP 1280                // per-bucket LDS list capacity

#define PROJ_LDS (128 * (TK + 1) * 4 + TK * F * 4)   // 33280 + 16384 = 49664 B

__global__ void classify_kernel(const int* __restrict__ node_type, int* __restrict__ tcnt,
                                int* __restrict__ list0, int* __restrict__ list1, int n) {
    int i = blockIdx.x * 256 + threadIdx.x;
    if (i < n) {
        int lane = threadIdx.x & 63;
        int t = node_type[i];
        unsigned long long b1 = __ballot(t == 1);
        unsigned long long ba = __ballot(1);
        unsigned long long mlt = (1ull << lane) - 1ull;
        int r1 = __popcll(b1 & mlt);
        int r0 = __popcll(ba & ~b1 & mlt);
        int base0, base1;
        if (lane == 0) {
            base1 = atomicAdd(&tcnt[1], __popcll(b1));
            base0 = atomicAdd(&tcnt[0], __popcll(ba & ~b1));
        }
        base0 = __shfl(base0, 0, 64);
        base1 = __shfl(base1, 0, 64);
        if (t == 1) list1[base1 + r1] = i;
        else        list0[base0 + r0] = i;
    }
}

__global__ __launch_bounds__(256, 2)
void proj_scatter(const float* __restrict__ d_sim, const float* __restrict__ m_sim,
                  const float* __restrict__ W_d, const float* __restrict__ W_m,
                  const int* __restrict__ tcnt, const int* __restrict__ list0,
                  const int* __restrict__ list1, unsigned short* __restrict__ zh,
                  const int* __restrict__ dst, const int* __restrict__ src,
                  int* __restrict__ bucket_count, int* __restrict__ bucket_data,
                  int e, int nbuk, int nsort) {
    __shared__ __align__(16) char smem[PROJ_LDS];    // union: proj 49664B / scatter 24576B
    int bid = blockIdx.x;

    if (bid < nsort) {
        // ---- bucket_scatter branch: 256 thr, 4 edges/thread via int4 ----
        int* hist  = (int*)smem;        // [2048]
        int* bbase = hist + 2048;       // [2048]
        int* rk    = bbase + 2048;      // [2048]
        for (int i = threadIdx.x; i < nbuk; i += 256) { hist[i] = 0; rk[i] = 0; }
        __syncthreads();
        int beg = bid * CHUNK, end = min(e, beg + CHUNK);
        for (int i = beg + (int)threadIdx.x * 4; i < end; i += 1024) {
            int4 d4 = *(const int4*)(dst + i);      // e mult of 4 assumed
            atomicAdd(&hist[d4.x >> BSH], 1);
            atomicAdd(&hist[d4.y >> BSH], 1);
            atomicAdd(&hist[d4.z >> BSH], 1);
            atomicAdd(&hist[d4.w >> BSH], 1);
        }
        __syncthreads();
        for (int i = threadIdx.x; i < nbuk; i += 256)
            bbase[i] = hist[i] ? atomicAdd(&bucket_count[i], hist[i]) : 0;
        __syncthreads();
        for (int i = beg + (int)threadIdx.x * 4; i < end; i += 1024) {
            int4 d4 = *(const int4*)(dst + i);
            int4 s4 = *(const int4*)(src + i);
            int b0 = d4.x >> BSH, b1 = d4.y >> BSH, b2 = d4.z >> BSH, b3 = d4.w >> BSH;
            int r0 = atomicAdd(&rk[b0], 1);
            int r1 = atomicAdd(&rk[b1], 1);
            int r2 = atomicAdd(&rk[b2], 1);
            int r3 = atomicAdd(&rk[b3], 1);
            int p0 = bbase[b0] + r0, p1 = bbase[b1] + r1;
            int p2 = bbase[b2] + r2, p3 = bbase[b3] + r3;
            if (p0 < CAP) bucket_data[(size_t)b0 * CAP + p0] = ((d4.x & 31) << 16) | s4.x;
            if (p1 < CAP) bucket_data[(size_t)b1 * CAP + p1] = ((d4.y & 31) << 16) | s4.y;
            if (p2 < CAP) bucket_data[(size_t)b2 * CAP + p2] = ((d4.z & 31) << 16) | s4.z;
            if (p3 < CAP) bucket_data[(size_t)b3 * CAP + p3] = ((d4.w & 31) << 16) | s4.w;
        }
        return;
    }

    // ------------------------- proj_gemm branch --------------------------
    int pb = bid - nsort;
    int ty = pb & 1;
    int cnt = tcnt[ty];
    int base = (pb >> 1) * TM;
    if (base >= cnt) return;
    const int*   list = ty ? list1 : list0;
    const float* A    = ty ? d_sim : m_sim;
    const float* W    = ty ? W_d   : W_m;

    float (*sA)[TK + 1] = (float (*)[TK + 1])smem;
    float (*sW)[F]      = (float (*)[F])(smem + 128 * (TK + 1) * 4);

    int rg = threadIdx.x >> 4;
    int cg = threadIdx.x & 15;

    int srow_node[8];
    #pragma unroll
    for (int j = 0; j < 8; j++) {
        int idx = (int)threadIdx.x + 256 * j;
        int li = base + (idx >> 4);
        if (li >= cnt) li = cnt - 1;
        srow_node[j] = list[li];
    }

    float acc[8][4] = {};
    for (int kc = 0; kc < 256; kc += TK) {
        __syncthreads();
        #pragma unroll
        for (int j = 0; j < 8; j++) {
            int idx = (int)threadIdx.x + 256 * j;
            int r = idx >> 4, f4 = idx & 15;
            float4 v = *(const float4*)(A + (size_t)srow_node[j] * 256 + kc + f4 * 4);
            sA[r][f4 * 4 + 0] = v.x;
            sA[r][f4 * 4 + 1] = v.y;
            sA[r][f4 * 4 + 2] = v.z;
            sA[r][f4 * 4 + 3] = v.w;
        }
        #pragma unroll
        for (int j = 0; j < 4; j++) {
            int idx = (int)threadIdx.x + 256 * j;
            int k = idx >> 4, f4 = idx & 15;
            float4 v = *(const float4*)(W + (size_t)(kc + k) * F + f4 * 4);
            *(float4*)&sW[k][f4 * 4] = v;
        }
        __syncthreads();
        #pragma unroll 4
        for (int k = 0; k < TK; k++) {
            float4 wv = *(const float4*)&sW[k][cg * 4];
            float a[8];
            #pragma unroll
            for (int i = 0; i < 8; i++) a[i] = sA[rg * 8 + i][k];
            #pragma unroll
            for (int i = 0; i < 8; i++) {
                acc[i][0] = fmaf(a[i], wv.x, acc[i][0]);
                acc[i][1] = fmaf(a[i], wv.y, acc[i][1]);
                acc[i][2] = fmaf(a[i], wv.z, acc[i][2]);
                acc[i][3] = fmaf(a[i], wv.w, acc[i][3]);
            }
        }
    }
    #pragma unroll
    for (int i = 0; i < 8; i++) {
        int li = base + rg * 8 + i;
        if (li < cnt) {
            int node = list[li];
            __half2 ha = __floats2half2_rn(acc[i][0], acc[i][1]);
            __half2 hb = __floats2half2_rn(acc[i][2], acc[i][3]);
            uint2 u;
            u.x = *(unsigned int*)&ha;
            u.y = *(unsigned int*)&hb;
            *(uint2*)(zh + (size_t)node * F + cg * 4) = u;   // 8B store, 16 lanes = 128B row
        }
    }
}

__global__ __launch_bounds__(512)
void attn_fused(const unsigned short* __restrict__ zh, const int* __restrict__ bucket_count,
                const int* __restrict__ bucket_data, float* __restrict__ out, int n) {
    __shared__ unsigned short ssrc[HCAP];
    __shared__ int cnt[32], excl[32], cur[32];
    int b = blockIdx.x;
    int dbase = b << BSH;
    const int* __restrict__ bd = bucket_data + (size_t)b * CAP;
    int len = min(bucket_count[b], CAP);
    int tid = threadIdx.x;

    if (tid < 32) { cnt[tid] = 0; cur[tid] = 0; }
    __syncthreads();
    // pass 1: per-dst counts (bucket holds only our 32 dsts)
    for (int i = tid; i < len; i += 512)
        atomicAdd(&cnt[bd[i] >> 16], 1);
    __syncthreads();
    if (tid < 32) {                   // 32-wide shfl exclusive scan (one wave)
        int v = cnt[tid];
        int s = v;
        #pragma unroll
        for (int off = 1; off < 32; off <<= 1) {
            int t = __shfl_up(s, off, 32);
            if (tid >= off) s += t;
        }
        excl[tid] = s - v;
    }
    __syncthreads();
    // pass 2: scatter srcs into LDS grouped by dst
    for (int i = tid; i < len; i += 512) {
        int v = bd[i];
        int d5 = v >> 16;
        int r = atomicAdd(&cur[d5], 1);
        int pos = excl[d5] + r;
        if (pos < HCAP) ssrc[pos] = (unsigned short)(v & 0xFFFF);
    }
    __syncthreads();

    // attention: wave wv handles dsts d5 = wv + 8k; 16 lanes/edge (R7 online
    // softmax) + R9 1-deep prefetch of next edge's ssrc + z row.
    int lane = tid & 63;
    int wv = tid >> 6;
    int g = lane >> 4, r = lane & 15;
    for (int k = 0; k < 4; k++) {
        int d5 = wv + 8 * k;
        int node = dbase + d5;
        if (node >= n) continue;
        int lbeg = excl[d5];
        int lcnt = min(cnt[d5], max(0, HCAP - lbeg));
        uint2 ud = *(const uint2*)(zh + (size_t)node * F + r * 4);
        float2 d0 = __half22float2(*(const __half2*)&ud.x);
        float2 d1 = __half22float2(*(const __half2*)&ud.y);
        float m = -3.402823466e38f, l = 0.f;
        float4 acc = {0.f, 0.f, 0.f, 0.f};
        if (lcnt > 0) {
            int s_c = ssrc[lbeg + min(g, lcnt - 1)];          // preload edge 0
            uint2 u_c = *(const uint2*)(zh + (size_t)s_c * F + r * 4);
            for (int j = 0; j < lcnt; j += 4) {
                // prefetch next iteration's edge (clamped: tail re-reads a
                // resident row -> no extra HBM fetch)
                int s_n = ssrc[lbeg + min(j + 4 + g, lcnt - 1)];
                uint2 u_n = *(const uint2*)(zh + (size_t)s_n * F + r * 4);
                int jj = j + g;
                float2 f0 = __half22float2(*(const __half2*)&u_c.x);
                float2 f1 = __half22float2(*(const __half2*)&u_c.y);
                float p = fmaf(f0.x, d0.x, fmaf(f0.y, d0.y, fmaf(f1.x, d1.x, f1.y * d1.y)));
                p += __shfl_xor(p, 1, 64);
                p += __shfl_xor(p, 2, 64);
                p += __shfl_xor(p, 4, 64);
                p += __shfl_xor(p, 8, 64);
                float e = (p > 0.f) ? p : 0.2f * p;       // leaky_relu
                if (jj >= lcnt) e = -INFINITY;
                float t = __expf(-fabsf(e - m));          // single-exp online update
                bool gt = (e > m);
                float sc = gt ? t : 1.f;
                float w  = gt ? 1.f : t;
                m = gt ? e : m;
                l = fmaf(l, sc, w);
                acc.x = fmaf(acc.x, sc, w * f0.x);
                acc.y = fmaf(acc.y, sc, w * f0.y);
                acc.z = fmaf(acc.z, sc, w * f1.x);
                acc.w = fmaf(acc.w, sc, w * f1.y);
                u_c = u_n;
            }
        }
        // merge the 4 groups
        #pragma unroll
        for (int off = 16; off <= 32; off <<= 1) {
            float om = __shfl_xor(m, off, 64);
            float ol = __shfl_xor(l, off, 64);
            float4 oa;
            oa.x = __shfl_xor(acc.x, off, 64);
            oa.y = __shfl_xor(acc.y, off, 64);
            oa.z = __shfl_xor(acc.z, off, 64);
            oa.w = __shfl_xor(acc.w, off, 64);
            float t = __expf(-fabsf(m - om));
            bool gt = (om > m);
            float sc = gt ? t : 1.f;
            float so = gt ? 1.f : t;
            m = gt ? om : m;
            l = fmaf(l, sc, ol * so);
            acc.x = fmaf(acc.x, sc, oa.x * so);
            acc.y = fmaf(acc.y, sc, oa.y * so);
            acc.z = fmaf(acc.z, sc, oa.z * so);
            acc.w = fmaf(acc.w, sc, oa.w * so);
        }
        float inv = 1.f / fmaxf(l, 1e-16f);
        float4 o;
        o.x = acc.x * inv; o.y = acc.y * inv; o.z = acc.z * inv; o.w = acc.w * inv;
        o.x = (o.x > 0.f) ? o.x : (__expf(o.x) - 1.f);
        o.y = (o.y > 0.f) ? o.y : (__expf(o.y) - 1.f);
        o.z = (o.z > 0.f) ? o.z : (__expf(o.z) - 1.f);
        o.w = (o.w > 0.f) ? o.w : (__expf(o.w) - 1.f);
        if (g == 0) ((float4*)(out + (size_t)node * F))[r] = o;
    }
}

extern "C" void kernel_launch(void* const* d_in, const int* in_sizes, int n_in,
                              void* d_out, int out_size, void* d_ws, size_t ws_size,
                              hipStream_t stream) {
    const float* d_sim     = (const float*)d_in[0];
    const float* m_sim     = (const float*)d_in[1];
    const float* W_d       = (const float*)d_in[2];
    const float* W_m       = (const float*)d_in[3];
    const int*   node_type = (const int*)d_in[4];
    const int*   src       = (const int*)d_in[5];
    const int*   dst       = (const int*)d_in[6];
    float* out = (float*)d_out;

    const int N = in_sizes[4];
    const int E = in_sizes[5];
    const int NBUK = (N + 31) >> BSH;           // 1563 for N=50000 (<=2048 assumed)

    char* ws = (char*)d_ws;
    int*            tcnt   = (int*)ws;                          // 2
    int*            bcount = tcnt + 2;                          // 2048
    int             head   = (2 + 2048 + 3) & ~3;               // align to 16B
    unsigned short* zh     = (unsigned short*)(ws + (size_t)head * 4);  // N*F fp16
    int*            list0  = (int*)(zh + (size_t)N * F);        // N (offset mult of 128B)
    int*            list1  = list0 + N;                         // N
    int*            bdata  = list1 + N;                         // NBUK*CAP

    hipMemsetAsync(tcnt, 0, (size_t)(2 + 2048) * sizeof(int), stream);

    dim3 blk(256);
    classify_kernel<<<dim3((N + 255) / 256), blk, 0, stream>>>(node_type, tcnt, list0, list1, N);

    int nsort = (E + CHUNK - 1) / CHUNK;        // 306 for E=1.25M
    int pgrid = 2 * ((N + TM - 1) / TM);        // 782
    proj_scatter<<<dim3(nsort + pgrid), blk, 0, stream>>>(d_sim, m_sim, W_d, W_m,
                                                          tcnt, list0, list1, zh,
                                                          dst, src, bcount, bdata,
                                                          E, NBUK, nsort);
    attn_fused<<<dim3(NBUK), dim3(512), 0, stream>>>(zh, bcount, bdata, out, N);
}